// Round 7
// baseline (194.283 us; speedup 1.0000x reference)
//
#include <hip/hip_runtime.h>
#include <hip/hip_bf16.h>
#include <cstdint>

// BiasedMHA bf16-MFMA pipeline: B=4, N=1024, FEAT=512, H=8, HD=64.
// detect mask dtype -> convert to bf16 -> QKV GEMM (MFMA) -> V transpose
// (chunked PV-ready layout) -> fused attention (all-8-heads blocks, bias/mask
// consumed in natural layout via gload_lds, triple-buffer counted-vmcnt) ->
// out-proj GEMM (MFMA, fp32 out).  prep_bias/biasT round-trip ELIMINATED.

namespace {

constexpr int kN = 1024, kH = 8;
constexpr int kM = 4 * 1024;  // 4096 rows

typedef short bf16x8 __attribute__((ext_vector_type(8)));
typedef float f32x4 __attribute__((ext_vector_type(4)));
using u16 = unsigned short;

__device__ __forceinline__ u16 f2bf(float f) {
  union { float f; uint32_t i; } v;
  v.f = f;
  uint32_t r = v.i + 0x7fffu + ((v.i >> 16) & 1u);
  return (u16)(r >> 16);
}

__device__ __forceinline__ void gload_lds16(const void* g, void* l) {
  __builtin_amdgcn_global_load_lds(
      (__attribute__((address_space(1))) void*)g,
      (__attribute__((address_space(3))) void*)l, 16, 0, 0);
}
__device__ __forceinline__ void gload_lds4(const void* g, void* l) {
  __builtin_amdgcn_global_load_lds(
      (__attribute__((address_space(1))) void*)g,
      (__attribute__((address_space(3))) void*)l, 4, 0, 0);
}

// ---------------------------------------------------------------- mask dtype
__global__ void detect_mask_kernel(const unsigned char* __restrict__ m,
                                   int* __restrict__ flag) {
  __shared__ int red[256];
  int local = 0;
  for (int i = threadIdx.x; i < 65536; i += 256) local += (m[i] != 0) ? 1 : 0;
  red[threadIdx.x] = local;
  __syncthreads();
  for (int s = 128; s > 0; s >>= 1) {
    if ((int)threadIdx.x < s) red[threadIdx.x] += red[threadIdx.x + s];
    __syncthreads();
  }
  if (threadIdx.x == 0) *flag = (red[0] > 4915) ? 1 : 0;  // 7.5% threshold
}

// ------------------------------------------------------------------ convert
__global__ __launch_bounds__(256) void convert_kernel(
    const float* __restrict__ nd, const float* __restrict__ Wq,
    const float* __restrict__ Wk, const float* __restrict__ Wv,
    const float* __restrict__ Wo, u16* __restrict__ A16,
    u16* __restrict__ W16) {
  const int gi = blockIdx.x * 256 + threadIdx.x;  // float4 index
  const float* src;
  u16* dst;
  int off;
  if (gi < 524288) {
    src = nd; dst = A16; off = gi * 4;
  } else {
    const int w = (gi - 524288) >> 16;
    off = ((gi - 524288) & 65535) * 4;
    src = (w == 0) ? Wq : (w == 1) ? Wk : (w == 2) ? Wv : Wo;
    dst = W16 + (size_t)w * 262144;
  }
  const float4 v = *(const float4*)&src[off];
  ushort4 o;
  o.x = f2bf(v.x); o.y = f2bf(v.y); o.z = f2bf(v.z); o.w = f2bf(v.w);
  *(ushort4*)&dst[off] = o;
}

// ------------------------------------------------------------------- GEMM NT
template <int EPI>
__global__ __launch_bounds__(256) void gemm_nt(
    const u16* __restrict__ A16, const u16* __restrict__ W16,
    const float* __restrict__ bq, const float* __restrict__ bk,
    const float* __restrict__ bv, u16* __restrict__ Q16,
    u16* __restrict__ K16, u16* __restrict__ V16,
    const float* __restrict__ bo, float* __restrict__ OutF) {
  __shared__ u16 As[128 * 64];
  __shared__ u16 Ws[64 * 64];
  const int tid = threadIdx.x, lane = tid & 63, wid = tid >> 6;
  const int r0 = blockIdx.x * 128;
  int wsel, c0;
  const float* bias;
  float scale = 1.0f;
  if (EPI == 0) {
    wsel = blockIdx.y >> 3;
    c0 = (blockIdx.y & 7) * 64;
    bias = (wsel == 0) ? bq : (wsel == 1) ? bk : bv;
    if (wsel == 0) scale = 0.125f;  // hd^-0.5
  } else {
    wsel = 3;
    c0 = blockIdx.y * 64;
    bias = bo;
  }
  const u16* W = W16 + (size_t)wsel * (512 * 512);
  const int wm = (wid >> 1) * 64, wn = (wid & 1) * 32;

  f32x4 acc[4][2] = {};
  for (int k0 = 0; k0 < 512; k0 += 64) {
    __syncthreads();
#pragma unroll
    for (int p = 0; p < 4; ++p) {
      const int o = p * 4096 + tid * 16;
      const int row = o >> 7, kb = o & 127;
      gload_lds16((const char*)A16 + (size_t)(r0 + row) * 1024 + k0 * 2 +
                      (kb ^ ((row & 7) << 4)),
                  (char*)As + o);
    }
#pragma unroll
    for (int p = 0; p < 2; ++p) {
      const int o = p * 4096 + tid * 16;
      const int row = o >> 7, kb = o & 127;
      gload_lds16((const char*)W + (size_t)(c0 + row) * 1024 + k0 * 2 +
                      (kb ^ ((row & 7) << 4)),
                  (char*)Ws + o);
    }
    __syncthreads();
    bf16x8 af[4][2], bf[2][2];
#pragma unroll
    for (int mt = 0; mt < 4; ++mt)
#pragma unroll
      for (int ks = 0; ks < 2; ++ks) {
        const int row = wm + mt * 16 + (lane & 15);
        const int kb = ks * 64 + (lane >> 4) * 16;
        af[mt][ks] = *(const bf16x8*)((const char*)As + row * 128 +
                                      (kb ^ ((row & 7) << 4)));
      }
#pragma unroll
    for (int nt = 0; nt < 2; ++nt)
#pragma unroll
      for (int ks = 0; ks < 2; ++ks) {
        const int row = wn + nt * 16 + (lane & 15);
        const int kb = ks * 64 + (lane >> 4) * 16;
        bf[nt][ks] = *(const bf16x8*)((const char*)Ws + row * 128 +
                                      (kb ^ ((row & 7) << 4)));
      }
#pragma unroll
    for (int mt = 0; mt < 4; ++mt)
#pragma unroll
      for (int nt = 0; nt < 2; ++nt)
#pragma unroll
        for (int ks = 0; ks < 2; ++ks)
          acc[mt][nt] = __builtin_amdgcn_mfma_f32_16x16x32_bf16(
              af[mt][ks], bf[nt][ks], acc[mt][nt], 0, 0, 0);
  }
  float bvals[2];
#pragma unroll
  for (int nt = 0; nt < 2; ++nt)
    bvals[nt] = bias[c0 + wn + nt * 16 + (lane & 15)];
#pragma unroll
  for (int mt = 0; mt < 4; ++mt)
#pragma unroll
    for (int nt = 0; nt < 2; ++nt)
#pragma unroll
      for (int r = 0; r < 4; ++r) {
        const int row = r0 + wm + mt * 16 + (lane >> 4) * 4 + r;
        const int col = c0 + wn + nt * 16 + (lane & 15);
        const float v = (acc[mt][nt][r] + bvals[nt]) * scale;
        if (EPI == 0) {
          const int bb = row >> 10, n = row & 1023, hh = col >> 6,
                    hd = col & 63;
          u16* O = (wsel == 0) ? Q16 : (wsel == 1) ? K16 : V16;
          O[((size_t)(bb * 8 + hh) * 1024 + n) * 64 + hd] = f2bf(v);
        } else {
          OutF[(size_t)row * 512 + col] = v;
        }
      }
}

// -------------------------------------------------------------- V transpose
// V16 [b][h][n][64d] -> VtG chunked layout: per (b,h, jc=n>>4): 2048B plane
// [g4 = (n&15)>>2][d 0..63][4 x u16 (n&3)] -> PV B-frag LDS reads (d-major,
// stride 8B) are bank-conflict-free with NO swizzle.
__global__ __launch_bounds__(256) void vtrans(const u16* __restrict__ V16,
                                              u16* __restrict__ VtG) {
  __shared__ u16 T[64][72];
  const int bh = blockIdx.x, n0 = blockIdx.y * 64;
  const int t = threadIdx.x;
  const int nr = t >> 2, cc = (t & 3) * 16;  // nr = n-local row, cc = d base
  const u16* src = V16 + ((size_t)bh * 1024 + n0 + nr) * 64 + cc;
  *(bf16x8*)&T[nr][cc] = *(const bf16x8*)&src[0];
  *(bf16x8*)&T[nr][cc + 8] = *(const bf16x8*)&src[8];
  __syncthreads();
  // this thread outputs: d = nr (fixed), n = n0 + cc + e (e=0..15) -> one jc
  const int d = nr;
  const int jc = (n0 + cc) >> 4;
  u16 o8[16];
#pragma unroll
  for (int e = 0; e < 16; ++e) o8[e] = T[cc + e][d];
  char* basep = (char*)VtG + ((size_t)bh * 64 + jc) * 2048;
#pragma unroll
  for (int g4 = 0; g4 < 4; ++g4) {
    uint2 pk;
    memcpy(&pk, &o8[g4 * 4], 8);
    *(uint2*)(basep + g4 * 512 + d * 8) = pk;
  }
}

// --------------------------------------------------------- fused attention
// Block = (b, 16 q-rows) x ALL 8 heads; 512 thr = 8 waves, wave = head h.
// j-loop: 64 chunks of TJ=16. Per chunk, staged by zero-VGPR gload_lds into
// one of 3 LDS buffers (48KB each): K (16KB, src-XOR for conflict-free b128
// frag reads), Vt (16KB, layout pre-arranged), bias f32 (8KB, granule-XOR
// involution), mask (8KB region; u8 4B-granule XOR / i32 linear).
// Counted vmcnt(6) + raw s_barrier: 6 uniform loads/thread/chunk, 2 chunks
// in flight -> staging latency hidden (T3/T4). PV via 16x16x32 MFMA with
// k-slots >=16 zeroed on BOTH operands.
__global__ __launch_bounds__(512, 1) void attn_fused(
    const u16* __restrict__ Q16, const u16* __restrict__ K16,
    const u16* __restrict__ VtG, const float* __restrict__ bias,
    const unsigned char* __restrict__ mask8, const int* __restrict__ mask32,
    const int* __restrict__ flag, u16* __restrict__ Ow16) {
  extern __shared__ char LDSD[];
  constexpr int BUF = 49152;  // K 16K | Vt 16K | bias 8K | mask 8K
  const int tid = threadIdx.x, lane = tid & 63, h = tid >> 6;
  const int bid = blockIdx.x;
  // 2 XCDs per batch b: bid%8 = b*2 + (it&1) -> K/V of b stay in XCD L2
  const int b = (bid & 7) >> 1;
  const int it = ((bid >> 3) << 1) | (bid & 1);
  const int i0 = it * 16;
  const bool mu8 = (*flag != 0);

  const int j = lane & 15, g = lane >> 4;

  char* Ps = LDSD + 3 * BUF + h * 544;  // per-wave P: [gj4 (stride 136)][16i][8B]

  const u16* Qh = Q16 + (size_t)(b * 8 + h) * 65536;

  bf16x8 qf[2];
  {
    const int qi = i0 + j;
#pragma unroll
    for (int ks = 0; ks < 2; ++ks)
      qf[ks] = *(const bf16x8*)&Qh[(size_t)qi * 64 + ks * 32 + g * 8];
  }
  float mo[4], lo[4];
  f32x4 oacc[4] = {};
#pragma unroll
  for (int r = 0; r < 4; ++r) { mo[r] = -3e38f; lo[r] = 0.f; }

  // ---- staging constants (per thread)
  const int sK_h = tid >> 7;           // unused placeholder pattern below
  (void)sK_h;
  // bias/mask reader constants (hoisted): source granule g0 = 2j + (h>>2),
  // dest ls = g0 ^ ((g0>>3)&1) ^ g   (involution on bits 0-2)
  const int g0 = 2 * j + (h >> 2);
  const int lsr = g0 ^ ((g0 >> 3) & 1) ^ g;

  auto STAGE = [&](int buf, int jc) {
    char* base = LDSD + buf * BUF;
    // K: 2 x 16B. dest granule sd -> h-plane sd>>7, w = sd&127;
    // src granule = w ^ ((w>>3)&7)  (j-row XOR for conflict-free frag reads)
#pragma unroll
    for (int q = 0; q < 2; ++q) {
      const int sd = q * 512 + tid;
      const int hh = sd >> 7, w = sd & 127;
      gload_lds16((const char*)K16 + (size_t)(b * 8 + hh) * 131072 +
                      (size_t)jc * 2048 + (size_t)(w ^ ((w >> 3) & 7)) * 16,
                  base + sd * 16);
    }
    // Vt: 2 x 16B, linear (global layout pre-arranged)
#pragma unroll
    for (int q = 0; q < 2; ++q) {
      const int sd = q * 512 + tid;
      const int hh = sd >> 7, w = sd & 127;
      gload_lds16((const char*)VtG + ((size_t)(b * 8 + hh) * 64 + jc) * 2048 +
                      (size_t)w * 16,
                  base + 16384 + sd * 16);
    }
    // bias: 1 x 16B. dest granule dg in row i; src = dg ^ ((dg>>3)&1) ^ ((i>>2)&3)
    {
      const int i = tid >> 5, dg = tid & 31;
      const int sg = dg ^ ((dg >> 3) & 1) ^ ((i >> 2) & 3);
      gload_lds16((const char*)bias + (size_t)(b * 1024 + i0 + i) * 32768 +
                      (size_t)jc * 512 + (size_t)sg * 16,
                  base + 32768 + tid * 16);
    }
    // mask: 1 load (uniform count both paths)
    if (mu8) {
      const int i = tid >> 5, d4 = tid & 31;
      const int sg = d4 ^ ((d4 >> 3) & 1) ^ ((i >> 2) & 3);
      gload_lds4((const char*)mask8 + (size_t)(b * 1024 + i0 + i) * 8192 +
                     (size_t)jc * 128 + (size_t)sg * 4,
                 base + 40960 + tid * 4);
    } else {
      const int i = tid >> 5, o = (tid & 31) * 16;
      gload_lds16((const char*)mask32 + (size_t)(b * 1024 + i0 + i) * 32768 +
                      (size_t)jc * 512 + o,
                  base + 40960 + tid * 16);
    }
  };

  auto COMPUTE = [&](int buf) {
    const char* base = LDSD + buf * BUF;
    // ---- QK^T: S[16i x 16j] for head h
    f32x4 sa = {0.f, 0.f, 0.f, 0.f};
#pragma unroll
    for (int ks = 0; ks < 2; ++ks) {
      const int gr = j * 8 + ((ks * 4 + g) ^ (j & 7));
      const bf16x8 kf = *(const bf16x8*)(base + h * 0 + gr * 16);
      sa = __builtin_amdgcn_mfma_f32_16x16x32_bf16(qf[ks], kf, sa, 0, 0, 0);
    }
    // wait: K region is per-head! K LDS: [h][16j][128B] -> offset h*2048
    // (handled below; the loop above is replaced)
    (void)sa;
    f32x4 s2 = {0.f, 0.f, 0.f, 0.f};
#pragma unroll
    for (int ks = 0; ks < 2; ++ks) {
      const int gr = j * 8 + ((ks * 4 + g) ^ (j & 7));
      const bf16x8 kf = *(const bf16x8*)(base + h * 2048 + gr * 16);
      s2 = __builtin_amdgcn_mfma_f32_16x16x32_bf16(qf[ks], kf, s2, 0, 0, 0);
    }
    // ---- bias + mask -> s[r]
    float s[4];
#pragma unroll
    for (int r = 0; r < 4; ++r) {
      const int i = g * 4 + r;
      const float bb =
          *(const float*)(base + 32768 + i * 512 + lsr * 16 + (h & 3) * 4);
      bool mk;
      if (mu8)
        mk = (*(const unsigned char*)(base + 40960 + i * 128 + lsr * 4 +
                                      (h & 3)) != 0);
      else
        mk = (*(const int*)(base + 40960 + i * 512 + (j * 8 + h) * 4) != 0);
      s[r] = mk ? -1e30f : (s2[r] + bb);
    }
    // ---- online softmax (16 j per chunk; reduce over lane&15)
#pragma unroll
    for (int r = 0; r < 4; ++r) {
      float cm = s[r];
      cm = fmaxf(cm, __shfl_xor(cm, 1));
      cm = fmaxf(cm, __shfl_xor(cm, 2));
      cm = fmaxf(cm, __shfl_xor(cm, 4));
      cm = fmaxf(cm, __shfl_xor(cm, 8));
      const float mn = fmaxf(mo[r], cm);
      const float sc = __expf(mo[r] - mn);
      mo[r] = mn;
      const float pr = __expf(s[r] - mn);
      float rs = pr;
      rs += __shfl_xor(rs, 1);
      rs += __shfl_xor(rs, 2);
      rs += __shfl_xor(rs, 4);
      rs += __shfl_xor(rs, 8);
      lo[r] = lo[r] * sc + rs;
      // P write: [gj=j>>2 (stride 136)][i][ (j&3)*2 ]
      *(u16*)(Ps + (j >> 2) * 136 + (g * 4 + r) * 8 + (j & 3) * 2) = f2bf(pr);
#pragma unroll
      for (int dt = 0; dt < 4; ++dt) oacc[dt][r] *= sc;
    }
    // same-wave LDS RAW fence (P writes -> P reads); rule #18 sched fence
    asm volatile("s_waitcnt lgkmcnt(0)" ::: "memory");
    __builtin_amdgcn_sched_barrier(0);
    // ---- PV: O[16i x 64d] += P[16i x 16j] * V[16j x 64d]
    // 16x16x32 MFMA, k-slots 16..31 zeroed on BOTH operands.
    const int ii = j;          // PV-phase: lane&15 = i for A, = d-sub for B
    const int gq = g & 1;
    union { uint2 u[2]; bf16x8 v; } pa;
    pa.u[0] = *(const uint2*)(Ps + (2 * gq) * 136 + ii * 8);
    pa.u[1] = *(const uint2*)(Ps + (2 * gq + 1) * 136 + ii * 8);
    bf16x8 pf = (g < 2) ? pa.v : (bf16x8)(short)0;
#pragma unroll
    for (int dt = 0; dt < 4; ++dt) {
      const int d = dt * 16 + ii;
      union { uint2 u[2]; bf16x8 v; } vb;
      vb.u[0] =
          *(const uint2*)(base + 16384 + h * 2048 + (2 * gq) * 512 + d * 8);
      vb.u[1] = *(const uint2*)(base + 16384 + h * 2048 + (2 * gq + 1) * 512 +
                                d * 8);
      const bf16x8 vf = (g < 2) ? vb.v : (bf16x8)(short)0;
      oacc[dt] = __builtin_amdgcn_mfma_f32_16x16x32_bf16(pf, vf, oacc[dt], 0,
                                                         0, 0);
    }
  };

  // ---- pipeline: triple buffer, counted vmcnt (6 loads/thread/chunk)
  STAGE(0, 0);
  STAGE(1, 1);
  asm volatile("s_waitcnt vmcnt(6)" ::: "memory");
  __builtin_amdgcn_s_barrier();
  int cur = 0, stg = 2;
  for (int t = 0; t < 64; ++t) {
    if (t < 62) STAGE(stg, t + 2);
    COMPUTE(cur);
    if (t < 63) {
      if (t < 62)
        asm volatile("s_waitcnt vmcnt(6)" ::: "memory");
      else
        asm volatile("s_waitcnt vmcnt(0)" ::: "memory");
      __builtin_amdgcn_s_barrier();
    }
    cur = (cur == 2) ? 0 : cur + 1;
    stg = (stg == 2) ? 0 : stg + 1;
  }

  // ---- epilogue: divide + store O[b][i][h*64+d]
#pragma unroll
  for (int r = 0; r < 4; ++r) {
    const float rl = 1.0f / lo[r];
    const int i = i0 + g * 4 + r;
#pragma unroll
    for (int dt = 0; dt < 4; ++dt) {
      const int d = dt * 16 + j;
      Ow16[((size_t)(b * 1024 + i)) * 512 + h * 64 + d] =
          f2bf(oacc[dt][r] * rl);
    }
  }
}

}  // namespace

extern "C" void kernel_launch(void* const* d_in, const int* in_sizes, int n_in,
                              void* d_out, int out_size, void* d_ws,
                              size_t ws_size, hipStream_t stream) {
  const float* ndata = (const float*)d_in[0];
  const float* bias = (const float*)d_in[1];
  const void* mask = d_in[2];
  const float* Wq = (const float*)d_in[3];
  const float* bq = (const float*)d_in[4];
  const float* Wk = (const float*)d_in[5];
  const float* bk = (const float*)d_in[6];
  const float* Wv = (const float*)d_in[7];
  const float* bvp = (const float*)d_in[8];
  const float* Wo = (const float*)d_in[9];
  const float* bo = (const float*)d_in[10];
  float* out = (float*)d_out;

  u16* A16 = (u16*)d_ws;                 // 2097152 u16
  u16* W16 = A16 + 2097152;              // 1048576
  u16* Q16 = W16 + 1048576;              // 2097152 each
  u16* K16 = Q16 + 2097152;
  u16* V16 = K16 + 2097152;
  u16* Vt = V16 + 2097152;
  u16* Ow = Vt + 2097152;
  int* flag = (int*)(Ow + 2097152);

  const int lds_bytes = 3 * 49152 + 8 * 544;  // 151808
  hipFuncSetAttribute((const void*)attn_fused,
                      hipFuncAttributeMaxDynamicSharedMemorySize, lds_bytes);

  detect_mask_kernel<<<1, 256, 0, stream>>>((const unsigned char*)mask, flag);
  convert_kernel<<<3072, 256, 0, stream>>>(ndata, Wq, Wk, Wv, Wo, A16, W16);
  gemm_nt<0><<<dim3(32, 24), 256, 0, stream>>>(A16, W16, bq, bk, bvp, Q16, K16,
                                               V16, nullptr, nullptr);
  vtrans<<<dim3(32, 16), 256, 0, stream>>>(V16, Vt);
  attn_fused<<<256, 512, lds_bytes, stream>>>(Q16, K16, Vt, bias,
                                              (const unsigned char*)mask,
                                              (const int*)mask, flag, Ow);
  gemm_nt<1><<<dim3(32, 8), 256, 0, stream>>>(Ow, W16, nullptr, nullptr,
                                              nullptr, nullptr, nullptr,
                                              nullptr, bo, out);
}